// Round 3
// baseline (1085.762 us; speedup 1.0000x reference)
//
#include <hip/hip_runtime.h>
#include <hip/hip_bf16.h>
#include <cstdint>
#include <cstddef>

typedef __hip_bfloat16 bf16;

// ---------------- input dtype sniffer ----------------
// Reads first 1024 32-bit words of x. If data is bf16, the low 16 bits of each
// word are a real bf16 value (~N(0,1) => |v| in [2^-10, 2^10] almost surely).
// If data is fp32, the low 16 bits are mantissa garbage => random exponent,
// only ~8% land in that range. flag=1 means "inputs are bf16".
__global__ __launch_bounds__(256) void sniff_kernel(const unsigned int* __restrict__ xw,
                                                    int* __restrict__ flag) {
    __shared__ int cnt[256];
    int t = threadIdx.x;
    int c = 0;
    for (int i = t; i < 1024; i += 256) {
        unsigned int w = xw[i];
        unsigned int fb = (w & 0xffffu) << 16;
        float v = __uint_as_float(fb);
        float a = fabsf(v);
        if (a >= 0.0009765625f && a <= 1024.0f) c++;
    }
    cnt[t] = c;
    __syncthreads();
    for (int off = 128; off; off >>= 1) {
        if (t < off) cnt[t] += cnt[t + off];
        __syncthreads();
    }
    if (t == 0) flag[0] = (cnt[0] >= 512) ? 1 : 0;
}

// convert one input tensor (bf16 or fp32 per flag) to fp32 scratch
__global__ __launch_bounds__(256) void convert_kernel(const void* __restrict__ src,
                                                      float* __restrict__ dst, int n,
                                                      const int* __restrict__ flag) {
    int i = blockIdx.x * 256 + threadIdx.x;
    if (i >= n) return;
    if (*flag)
        dst[i] = __bfloat162float(((const bf16*)src)[i]);
    else
        dst[i] = ((const float*)src)[i];
}

// ---------------- CSR build ----------------
__global__ __launch_bounds__(256) void degree_kernel(const int* __restrict__ ei_dst,
                                                     int* __restrict__ deg, int E, int Etot) {
    int e = blockIdx.x * 256 + threadIdx.x;
    if (e >= Etot) return;
    int d = (e < E) ? ei_dst[e] : (e - E);
    atomicAdd(&deg[d], 1);
}

__global__ __launch_bounds__(1024) void scan_kernel(const int* __restrict__ deg,
                                                    int* __restrict__ rowoff, int n) {
    __shared__ int sums[1024];
    int t = threadIdx.x;
    int chunk = (n + 1023) >> 10;
    int start = t * chunk;
    int end = min(start + chunk, n);
    int s = 0;
    for (int i = start; i < end; i++) s += deg[i];
    sums[t] = s;
    __syncthreads();
    for (int off = 1; off < 1024; off <<= 1) {
        int v = (t >= off) ? sums[t - off] : 0;
        __syncthreads();
        sums[t] += v;
        __syncthreads();
    }
    int base = (t == 0) ? 0 : sums[t - 1];
    for (int i = start; i < end; i++) { rowoff[i] = base; base += deg[i]; }
    if (t == 1023) rowoff[n] = sums[1023];
}

__global__ __launch_bounds__(256) void scatter_kernel(const int* __restrict__ ei_src,
                                                      const int* __restrict__ ei_dst,
                                                      const int* __restrict__ rowoff,
                                                      int* __restrict__ cursor,
                                                      int* __restrict__ ssrc, int E, int Etot) {
    int e = blockIdx.x * 256 + threadIdx.x;
    if (e >= Etot) return;
    int s, d;
    if (e < E) { s = ei_src[e]; d = ei_dst[e]; } else { s = d = e - E; }
    int pos = rowoff[d] + atomicAdd(&cursor[d], 1);
    ssrc[pos] = s;
}

// ---------------- GEMM: C[M,N2] = A[M,K] @ W[K,N2] ----------------
// DYNA: A may be bf16 (per *flag). EPI: add bias + ReLU. Output always fp32.
template <bool EPI, bool DYNA>
__global__ __launch_bounds__(256) void gemm_kernel(const float* __restrict__ A,
                                                   const bf16* __restrict__ Ab,
                                                   const int* __restrict__ flag,
                                                   const float* __restrict__ W,
                                                   float* __restrict__ C,
                                                   const float* __restrict__ bias,
                                                   int M, int K, int N2) {
    __shared__ float sA[16][65];
    __shared__ float sB[16][65];
    const int tid = threadIdx.x;
    const int tx = tid & 15, ty = tid >> 4;
    const int bm = blockIdx.x * 64, bn = blockIdx.y * 64;
    const bool isb = DYNA ? (*flag != 0) : false;
    float acc[4][4] = {};
    for (int k0 = 0; k0 < K; k0 += 16) {
#pragma unroll
        for (int l = 0; l < 4; l++) {
            int idx = l * 256 + tid;
            int kk = idx & 15, mm = idx >> 4;
            int gm = bm + mm;
            float v = 0.f;
            if (gm < M) {
                size_t off = (size_t)gm * K + k0 + kk;
                v = (DYNA && isb) ? __bfloat162float(Ab[off]) : A[off];
            }
            sA[kk][mm] = v;
        }
#pragma unroll
        for (int l = 0; l < 4; l++) {
            int idx = l * 256 + tid;
            int nn = idx & 63, kk = idx >> 6;
            sB[kk][nn] = W[(size_t)(k0 + kk) * N2 + bn + nn];
        }
        __syncthreads();
#pragma unroll
        for (int kk = 0; kk < 16; kk++) {
            float a[4], b[4];
#pragma unroll
            for (int i = 0; i < 4; i++) a[i] = sA[kk][ty * 4 + i];
#pragma unroll
            for (int j = 0; j < 4; j++) b[j] = sB[kk][tx * 4 + j];
#pragma unroll
            for (int i = 0; i < 4; i++)
#pragma unroll
                for (int j = 0; j < 4; j++) acc[i][j] += a[i] * b[j];
        }
        __syncthreads();
    }
#pragma unroll
    for (int i = 0; i < 4; i++) {
        int gm = bm + ty * 4 + i;
        if (gm >= M) continue;
#pragma unroll
        for (int j = 0; j < 4; j++) {
            int gn = bn + tx * 4 + j;
            float v = acc[i][j];
            if (EPI) {
                v += bias[gn];
                v = v > 0.f ? v : 0.f;
            }
            C[(size_t)gm * N2 + gn] = v;
        }
    }
}

// ---------------- attention per-node coefficients ----------------
__global__ __launch_bounds__(256) void attn_kernel(const float* __restrict__ xl,
                                                   const float* __restrict__ a_src,
                                                   const float* __restrict__ a_dst,
                                                   float* __restrict__ as_n,
                                                   float* __restrict__ ad_n, int NH, int H) {
    int w = blockIdx.x * 4 + (threadIdx.x >> 6);
    int lane = threadIdx.x & 63;
    if (w >= NH) return;
    int n = w / H, h = w - n * H;
    float xv = xl[(size_t)n * (H * 64) + h * 64 + lane];
    float s = xv * a_src[h * 64 + lane];
    float d = xv * a_dst[h * 64 + lane];
#pragma unroll
    for (int off = 32; off; off >>= 1) {
        s += __shfl_xor(s, off, 64);
        d += __shfl_xor(d, off, 64);
    }
    if (lane == 0) { as_n[w] = s; ad_n[w] = d; }
}

// ---------------- per-dst softmax-weighted aggregation ----------------
template <int H>
__global__ __launch_bounds__(256) void aggregate_kernel(const float* __restrict__ xl,
                                                        const float* __restrict__ as_n,
                                                        const float* __restrict__ ad_n,
                                                        const int* __restrict__ rowoff,
                                                        const int* __restrict__ ssrc,
                                                        const float* __restrict__ bias,
                                                        float* __restrict__ hout, int N) {
    int d = blockIdx.x * 4 + (threadIdx.x >> 6);
    int lane = threadIdx.x & 63;
    if (d >= N) return;
    int r0 = rowoff[d], r1 = rowoff[d + 1];
    float adv[H], acc[H], den[H];
#pragma unroll
    for (int h = 0; h < H; h++) {
        adv[h] = ad_n[d * H + h];
        acc[h] = 0.f;
        den[h] = 0.f;
    }
    for (int i = r0; i < r1; i++) {
        int s = ssrc[i];
#pragma unroll
        for (int h = 0; h < H; h++) {
            float lg = as_n[s * H + h] + adv[h];
            lg = lg > 0.f ? lg : 0.2f * lg;  // leaky relu
            float p = __expf(lg);            // softmax shift dropped (shift-invariant)
            den[h] += p;
            acc[h] += p * xl[(size_t)s * (H * 64) + h * 64 + lane];
        }
    }
#pragma unroll
    for (int h = 0; h < H; h++) {
        float v = acc[h] / (den[h] + 1e-16f) + bias[h * 64 + lane];
        hout[(size_t)d * (H * 64) + h * 64 + lane] = v > 0.f ? v : 0.f;
    }
}

extern "C" void kernel_launch(void* const* d_in, const int* in_sizes, int n_in,
                              void* d_out, int out_size, void* d_ws, size_t ws_size,
                              hipStream_t stream) {
    const int N = in_sizes[0] / 128;  // 50000
    const int E = in_sizes[1] / 2;    // 800000
    const int Etot = E + N;

    const int* ei = (const int*)d_in[1];
    const int* ei_src = ei;
    const int* ei_dst = ei + E;
    float* out = (float*)d_out;  // reference output dtype = fp32

    // workspace layout (fp32 elems, then int elems)
    float* bufA = (float*)d_ws;                 // N*256
    float* bufB = bufA + (size_t)N * 256;       // N*256
    float* asn  = bufB + (size_t)N * 256;       // N*4
    float* adn  = asn + (size_t)N * 4;          // N*4
    float* wts  = adn + (size_t)N * 4;          // 149,696 converted weights
    // weight scratch offsets
    float* W1  = wts;            // 32768
    float* as1 = W1 + 32768;     // 256
    float* ad1 = as1 + 256;      // 256
    float* b1  = ad1 + 256;      // 256
    float* W2  = b1 + 256;       // 65536
    float* as2 = W2 + 65536;     // 256
    float* ad2 = as2 + 256;      // 256
    float* b2  = ad2 + 256;      // 256
    float* W3  = b2 + 256;       // 16384
    float* as3 = W3 + 16384;     // 64
    float* ad3 = as3 + 64;       // 64
    float* b3  = ad3 + 64;       // 64
    float* Wfc = b3 + 64;        // 32768
    float* bfc = Wfc + 32768;    // 512
    int* deg    = (int*)(bfc + 512);  // N
    int* rowoff = deg + N;            // N+1
    int* cursor = rowoff + N + 1;     // N
    int* ssrc   = cursor + N;         // Etot
    int* flag   = ssrc + Etot;        // 1

    // 1. sniff input dtype (bf16 vs fp32) from x
    sniff_kernel<<<1, 256, 0, stream>>>((const unsigned int*)d_in[0], flag);

    // 2. convert all weight tensors to fp32 scratch
    {
        float* dsts[14] = {W1, as1, ad1, b1, W2, as2, ad2, b2, W3, as3, ad3, b3, Wfc, bfc};
        for (int i = 0; i < 14; i++) {
            int n = in_sizes[i + 2];
            convert_kernel<<<(n + 255) / 256, 256, 0, stream>>>(d_in[i + 2], dsts[i], n, flag);
        }
    }

    // 3. CSR build
    hipMemsetAsync(deg, 0, (size_t)(3 * N + 1) * sizeof(int), stream);
    int eb = (Etot + 255) / 256;
    degree_kernel<<<eb, 256, 0, stream>>>(ei_dst, deg, E, Etot);
    scan_kernel<<<1, 1024, 0, stream>>>(deg, rowoff, N);
    scatter_kernel<<<eb, 256, 0, stream>>>(ei_src, ei_dst, rowoff, cursor, ssrc, E, Etot);

    dim3 g1((N + 63) / 64, 4);
    dim3 g3((N + 63) / 64, 1);
    dim3 gf((N + 63) / 64, 8);
    int ab4 = (N * 4 + 3) / 4;
    int ab1 = (N + 3) / 4;
    int gb = (N + 3) / 4;

    // layer 1: x @ W1 -> bufB; attn; aggregate -> bufA
    gemm_kernel<false, true><<<g1, 256, 0, stream>>>((const float*)d_in[0], (const bf16*)d_in[0],
                                                     flag, W1, bufB, nullptr, N, 128, 256);
    attn_kernel<<<ab4, 256, 0, stream>>>(bufB, as1, ad1, asn, adn, N * 4, 4);
    aggregate_kernel<4><<<gb, 256, 0, stream>>>(bufB, asn, adn, rowoff, ssrc, b1, bufA, N);

    // layer 2
    gemm_kernel<false, false><<<g1, 256, 0, stream>>>(bufA, nullptr, flag, W2, bufB, nullptr,
                                                      N, 256, 256);
    attn_kernel<<<ab4, 256, 0, stream>>>(bufB, as2, ad2, asn, adn, N * 4, 4);
    aggregate_kernel<4><<<gb, 256, 0, stream>>>(bufB, asn, adn, rowoff, ssrc, b2, bufA, N);

    // layer 3 (H=1, C=64)
    gemm_kernel<false, false><<<g3, 256, 0, stream>>>(bufA, nullptr, flag, W3, bufB, nullptr,
                                                      N, 256, 64);
    attn_kernel<<<ab1, 256, 0, stream>>>(bufB, as3, ad3, asn, adn, N, 1);
    aggregate_kernel<1><<<gb, 256, 0, stream>>>(bufB, asn, adn, rowoff, ssrc, b3, bufA, N);

    // final fc: relu(bufA[N,64] @ Wfc + bfc) -> fp32 out
    gemm_kernel<true, false><<<gf, 256, 0, stream>>>(bufA, nullptr, flag, Wfc, out, bfc,
                                                     N, 64, 512);
}

// Round 6
// 835.155 us; speedup vs baseline: 1.3001x; 1.3001x over previous
//
#include <hip/hip_runtime.h>
#include <cstdint>
#include <cstddef>

typedef unsigned short ushort_t;
typedef __bf16 bf16x8 __attribute__((ext_vector_type(8)));
typedef float f32x4 __attribute__((ext_vector_type(4)));

__device__ __forceinline__ ushort_t f2b(float f) {
    __bf16 h = (__bf16)f;  // RNE
    return *(ushort_t*)&h;
}

// stage 8 contiguous fp32 elements into LDS as bf16
__device__ __forceinline__ void stage8f(const float* __restrict__ g, ushort_t* s) {
    float4 f0 = *(const float4*)g;
    float4 f1 = *(const float4*)(g + 4);
    union { ushort_t u[8]; uint4 v; } t;
    t.u[0] = f2b(f0.x); t.u[1] = f2b(f0.y); t.u[2] = f2b(f0.z); t.u[3] = f2b(f0.w);
    t.u[4] = f2b(f1.x); t.u[5] = f2b(f1.y); t.u[6] = f2b(f1.z); t.u[7] = f2b(f1.w);
    *(uint4*)s = t.v;
}
// stage 8 contiguous bf16 elements (pre-converted weights): raw 16B copy
__device__ __forceinline__ void stage8b(const ushort_t* __restrict__ g, ushort_t* s) {
    *(float4*)s = *(const float4*)g;
}

// ---------------- weight transpose+convert: WT[n][k] = bf16(W[k][n]) ----------------
__global__ __launch_bounds__(256) void transpose_kernel(const float* __restrict__ W,
                                                        ushort_t* __restrict__ WT,
                                                        int K, int N2) {
    int id = blockIdx.x * 256 + threadIdx.x;
    if (id >= K * N2) return;
    int n = id / K, k = id - n * K;
    WT[id] = f2b(W[k * N2 + n]);
}

// ---------------- CSR build (verbatim from passing round 3) ----------------
__global__ __launch_bounds__(256) void degree_kernel(const int* __restrict__ ei_dst,
                                                     int* __restrict__ deg, int E, int Etot) {
    int e = blockIdx.x * 256 + threadIdx.x;
    if (e >= Etot) return;
    int d = (e < E) ? ei_dst[e] : (e - E);
    atomicAdd(&deg[d], 1);
}

__global__ __launch_bounds__(1024) void scan_kernel(const int* __restrict__ deg,
                                                    int* __restrict__ rowoff, int n) {
    __shared__ int sums[1024];
    int t = threadIdx.x;
    int chunk = (n + 1023) >> 10;
    int start = t * chunk;
    int end = min(start + chunk, n);
    int s = 0;
    for (int i = start; i < end; i++) s += deg[i];
    sums[t] = s;
    __syncthreads();
    for (int off = 1; off < 1024; off <<= 1) {
        int v = (t >= off) ? sums[t - off] : 0;
        __syncthreads();
        sums[t] += v;
        __syncthreads();
    }
    int base = (t == 0) ? 0 : sums[t - 1];
    for (int i = start; i < end; i++) { rowoff[i] = base; base += deg[i]; }
    if (t == 1023) rowoff[n] = sums[1023];
}

__global__ __launch_bounds__(256) void scatter_kernel(const int* __restrict__ ei_src,
                                                      const int* __restrict__ ei_dst,
                                                      const int* __restrict__ rowoff,
                                                      int* __restrict__ cursor,
                                                      int* __restrict__ ssrc, int E, int Etot) {
    int e = blockIdx.x * 256 + threadIdx.x;
    if (e >= Etot) return;
    int s, d;
    if (e < E) { s = ei_src[e]; d = ei_dst[e]; } else { s = d = e - E; }
    int pos = rowoff[d] + atomicAdd(&cursor[d], 1);
    ssrc[pos] = s;
}

// ---------------- MFMA GEMM: C[M,N2](fp32) = A[M,K](fp32) @ WT[N2,K](bf16)^T ----
// BM=64, BN=64, BK=32; 256 thr = 4 waves; wave w owns rows w*16..w*16+15.
// A-frag: lane holds A[m=lane&15][k=quad*8+j]; B-frag: B[n=lane&15][k=quad*8+j];
// C/D: col=lane&15, row=quad*4+reg (m89/m91-verified).
template <bool EPI>
__global__ __launch_bounds__(256) void gemm_mfma(const float* __restrict__ A,
                                                 const ushort_t* __restrict__ WT,
                                                 float* __restrict__ C,
                                                 const float* __restrict__ bias,
                                                 int M, int K, int N2) {
    __shared__ ushort_t sA[64 * 32];  // 4 KB
    __shared__ ushort_t sB[64 * 32];  // 4 KB
    const int tid = threadIdx.x;
    const int wv = tid >> 6, lane = tid & 63;
    const int quad = lane >> 4, l16 = lane & 15;
    const int bm = blockIdx.x * 64, bn = blockIdx.y * 64;
    const int srow = tid >> 2, skof = (tid & 3) * 8;  // each thread stages 8 elems
    f32x4 acc[4] = {};

    for (int k0 = 0; k0 < K; k0 += 32) {
        int gm = bm + srow;
        gm = gm < M ? gm : M - 1;  // clamp tail rows (dup read, epilogue masks)
        stage8f(A + (size_t)gm * K + k0 + skof, sA + srow * 32 + skof);
        stage8b(WT + (size_t)(bn + srow) * K + k0 + skof, sB + srow * 32 + skof);
        __syncthreads();

        bf16x8 af = *(const bf16x8*)(sA + (wv * 16 + l16) * 32 + quad * 8);
#pragma unroll
        for (int j = 0; j < 4; j++) {
            bf16x8 bf = *(const bf16x8*)(sB + (j * 16 + l16) * 32 + quad * 8);
            acc[j] = __builtin_amdgcn_mfma_f32_16x16x32_bf16(af, bf, acc[j], 0, 0, 0);
        }
        __syncthreads();
    }

#pragma unroll
    for (int j = 0; j < 4; j++) {
        int col = bn + j * 16 + l16;
        float bv = EPI ? bias[col] : 0.f;
#pragma unroll
        for (int r = 0; r < 4; r++) {
            int row = bm + wv * 16 + quad * 4 + r;
            if (row < M) {
                float v = acc[j][r] + bv;
                if (EPI) v = v > 0.f ? v : 0.f;
                C[(size_t)row * N2 + col] = v;
            }
        }
    }
}

// ---------------- attention per-node coefficients (verbatim round 3) ----------------
__global__ __launch_bounds__(256) void attn_kernel(const float* __restrict__ xl,
                                                   const float* __restrict__ a_src,
                                                   const float* __restrict__ a_dst,
                                                   float* __restrict__ as_n,
                                                   float* __restrict__ ad_n, int NH, int H) {
    int w = blockIdx.x * 4 + (threadIdx.x >> 6);
    int lane = threadIdx.x & 63;
    if (w >= NH) return;
    int n = w / H, h = w - n * H;
    float xv = xl[(size_t)n * (H * 64) + h * 64 + lane];
    float s = xv * a_src[h * 64 + lane];
    float d = xv * a_dst[h * 64 + lane];
#pragma unroll
    for (int off = 32; off; off >>= 1) {
        s += __shfl_xor(s, off, 64);
        d += __shfl_xor(d, off, 64);
    }
    if (lane == 0) { as_n[w] = s; ad_n[w] = d; }
}

// ---------------- per-dst softmax-weighted aggregation (verbatim round 3) ----------------
template <int H>
__global__ __launch_bounds__(256) void aggregate_kernel(const float* __restrict__ xl,
                                                        const float* __restrict__ as_n,
                                                        const float* __restrict__ ad_n,
                                                        const int* __restrict__ rowoff,
                                                        const int* __restrict__ ssrc,
                                                        const float* __restrict__ bias,
                                                        float* __restrict__ hout, int N) {
    int d = blockIdx.x * 4 + (threadIdx.x >> 6);
    int lane = threadIdx.x & 63;
    if (d >= N) return;
    int r0 = rowoff[d], r1 = rowoff[d + 1];
    float adv[H], acc[H], den[H];
#pragma unroll
    for (int h = 0; h < H; h++) {
        adv[h] = ad_n[d * H + h];
        acc[h] = 0.f;
        den[h] = 0.f;
    }
    for (int i = r0; i < r1; i++) {
        int s = ssrc[i];
#pragma unroll
        for (int h = 0; h < H; h++) {
            float lg = as_n[s * H + h] + adv[h];
            lg = lg > 0.f ? lg : 0.2f * lg;  // leaky relu
            float p = __expf(lg);            // softmax shift dropped (shift-invariant)
            den[h] += p;
            acc[h] += p * xl[(size_t)s * (H * 64) + h * 64 + lane];
        }
    }
#pragma unroll
    for (int h = 0; h < H; h++) {
        float v = acc[h] / (den[h] + 1e-16f) + bias[h * 64 + lane];
        hout[(size_t)d * (H * 64) + h * 64 + lane] = v > 0.f ? v : 0.f;
    }
}

extern "C" void kernel_launch(void* const* d_in, const int* in_sizes, int n_in,
                              void* d_out, int out_size, void* d_ws, size_t ws_size,
                              hipStream_t stream) {
    const int N = in_sizes[0] / 128;  // 50000
    const int E = in_sizes[1] / 2;    // 800000
    const int Etot = E + N;

    const float* x = (const float*)d_in[0];  // fp32 input
    const int* ei = (const int*)d_in[1];
    const int* ei_src = ei;
    const int* ei_dst = ei + E;
    float* out = (float*)d_out;  // fp32 output

    const float* as1 = (const float*)d_in[3];
    const float* ad1 = (const float*)d_in[4];
    const float* b1  = (const float*)d_in[5];
    const float* as2 = (const float*)d_in[7];
    const float* ad2 = (const float*)d_in[8];
    const float* b2  = (const float*)d_in[9];
    const float* as3 = (const float*)d_in[11];
    const float* ad3 = (const float*)d_in[12];
    const float* b3  = (const float*)d_in[13];
    const float* bfc = (const float*)d_in[15];

    // ---- workspace layout ----
    float* bufA = (float*)d_ws;                  // N*256 fp32 (agg out)
    float* bufB = bufA + (size_t)N * 256;        // N*256 fp32 (xl)
    float* asn  = bufB + (size_t)N * 256;        // N*4
    float* adn  = asn + (size_t)N * 4;           // N*4
    ushort_t* W1T  = (ushort_t*)(adn + (size_t)N * 4);  // 256x128 bf16
    ushort_t* W2T  = W1T + 32768;                // 256x256
    ushort_t* W3T  = W2T + 65536;                // 64x256
    ushort_t* WfcT = W3T + 16384;                // 512x64
    int* deg    = (int*)(WfcT + 32768);          // N
    int* rowoff = deg + N;                       // N+1
    int* cursor = rowoff + N + 1;                // N
    int* ssrc   = cursor + N;                    // Etot

    // weight transposes+converts (fp32 [K][N] -> bf16 [N][K])
    transpose_kernel<<<(128 * 256 + 255) / 256, 256, 0, stream>>>((const float*)d_in[2], W1T, 128, 256);
    transpose_kernel<<<(256 * 256 + 255) / 256, 256, 0, stream>>>((const float*)d_in[6], W2T, 256, 256);
    transpose_kernel<<<(256 * 64 + 255) / 256, 256, 0, stream>>>((const float*)d_in[10], W3T, 256, 64);
    transpose_kernel<<<(64 * 512 + 255) / 256, 256, 0, stream>>>((const float*)d_in[14], WfcT, 64, 512);

    // CSR build
    hipMemsetAsync(deg, 0, (size_t)(3 * N + 1) * sizeof(int), stream);
    int eb = (Etot + 255) / 256;
    degree_kernel<<<eb, 256, 0, stream>>>(ei_dst, deg, E, Etot);
    scan_kernel<<<1, 1024, 0, stream>>>(deg, rowoff, N);
    scatter_kernel<<<eb, 256, 0, stream>>>(ei_src, ei_dst, rowoff, cursor, ssrc, E, Etot);

    const int MB = (N + 63) / 64;  // 782
    int ab4 = (N * 4 + 3) / 4;
    int ab1 = (N + 3) / 4;
    int gb = (N + 3) / 4;

    // layer 1: x @ W1 -> bufB; attn; aggregate -> bufA
    gemm_mfma<false><<<dim3(MB, 4), 256, 0, stream>>>(x, W1T, bufB, nullptr, N, 128, 256);
    attn_kernel<<<ab4, 256, 0, stream>>>(bufB, as1, ad1, asn, adn, N * 4, 4);
    aggregate_kernel<4><<<gb, 256, 0, stream>>>(bufB, asn, adn, rowoff, ssrc, b1, bufA, N);

    // layer 2
    gemm_mfma<false><<<dim3(MB, 4), 256, 0, stream>>>(bufA, W2T, bufB, nullptr, N, 256, 256);
    attn_kernel<<<ab4, 256, 0, stream>>>(bufB, as2, ad2, asn, adn, N * 4, 4);
    aggregate_kernel<4><<<gb, 256, 0, stream>>>(bufB, asn, adn, rowoff, ssrc, b2, bufA, N);

    // layer 3 (H=1, C=64)
    gemm_mfma<false><<<dim3(MB, 1), 256, 0, stream>>>(bufA, W3T, bufB, nullptr, N, 256, 64);
    attn_kernel<<<ab1, 256, 0, stream>>>(bufB, as3, ad3, asn, adn, N, 1);
    aggregate_kernel<1><<<gb, 256, 0, stream>>>(bufB, asn, adn, rowoff, ssrc, b3, bufA, N);

    // final fc: relu(bufA[N,64] @ Wfc + bfc) -> fp32 out
    gemm_mfma<true><<<dim3(MB, 8), 256, 0, stream>>>(bufA, WfcT, out, bfc, N, 64, 512);
}

// Round 7
// 690.488 us; speedup vs baseline: 1.5725x; 1.2095x over previous
//
#include <hip/hip_runtime.h>
#include <cstdint>
#include <cstddef>

typedef unsigned short ushort_t;
typedef __bf16 bf16x8 __attribute__((ext_vector_type(8)));
typedef float f32x4 __attribute__((ext_vector_type(4)));

__device__ __forceinline__ float b2f(ushort_t u) {
    return __uint_as_float(((unsigned int)u) << 16);
}
__device__ __forceinline__ ushort_t f2b(float f) {
    __bf16 h = (__bf16)f;  // RNE
    return *(ushort_t*)&h;
}

// stage 8 contiguous elements into LDS as bf16 (overloaded on source type)
__device__ __forceinline__ void stage8(const float* __restrict__ g, ushort_t* s) {
    float4 f0 = *(const float4*)g;
    float4 f1 = *(const float4*)(g + 4);
    union { ushort_t u[8]; uint4 v; } t;
    t.u[0] = f2b(f0.x); t.u[1] = f2b(f0.y); t.u[2] = f2b(f0.z); t.u[3] = f2b(f0.w);
    t.u[4] = f2b(f1.x); t.u[5] = f2b(f1.y); t.u[6] = f2b(f1.z); t.u[7] = f2b(f1.w);
    *(uint4*)s = t.v;
}
__device__ __forceinline__ void stage8(const ushort_t* __restrict__ g, ushort_t* s) {
    *(float4*)s = *(const float4*)g;  // already bf16: raw 16B copy
}

// ---------------- weight transpose+convert: WT[n][k] = bf16(W[k][n]) ----------------
__global__ __launch_bounds__(256) void transpose_kernel(const float* __restrict__ W,
                                                        ushort_t* __restrict__ WT,
                                                        int K, int N2) {
    int id = blockIdx.x * 256 + threadIdx.x;
    if (id >= K * N2) return;
    int n = id / K, k = id - n * K;
    WT[id] = f2b(W[k * N2 + n]);
}

// ---------------- CSR build ----------------
__global__ __launch_bounds__(256) void degree_kernel(const int* __restrict__ ei_dst,
                                                     int* __restrict__ deg, int E, int Etot) {
    int e = blockIdx.x * 256 + threadIdx.x;
    if (e >= Etot) return;
    int d = (e < E) ? ei_dst[e] : (e - E);
    atomicAdd(&deg[d], 1);
}

__global__ __launch_bounds__(1024) void scan_kernel(const int* __restrict__ deg,
                                                    int* __restrict__ rowoff, int n) {
    __shared__ int sums[1024];
    int t = threadIdx.x;
    int chunk = (n + 1023) >> 10;
    int start = t * chunk;
    int end = min(start + chunk, n);
    int s = 0;
    for (int i = start; i < end; i++) s += deg[i];
    sums[t] = s;
    __syncthreads();
    for (int off = 1; off < 1024; off <<= 1) {
        int v = (t >= off) ? sums[t - off] : 0;
        __syncthreads();
        sums[t] += v;
        __syncthreads();
    }
    int base = (t == 0) ? 0 : sums[t - 1];
    for (int i = start; i < end; i++) { rowoff[i] = base; base += deg[i]; }
    if (t == 1023) rowoff[n] = sums[1023];
}

__global__ __launch_bounds__(256) void scatter_kernel(const int* __restrict__ ei_src,
                                                      const int* __restrict__ ei_dst,
                                                      const int* __restrict__ rowoff,
                                                      int* __restrict__ cursor,
                                                      int* __restrict__ ssrc, int E, int Etot) {
    int e = blockIdx.x * 256 + threadIdx.x;
    if (e >= Etot) return;
    int s, d;
    if (e < E) { s = ei_src[e]; d = ei_dst[e]; } else { s = d = e - E; }
    int pos = rowoff[d] + atomicAdd(&cursor[d], 1);
    ssrc[pos] = s;
}

// ---------------- MFMA GEMM: C = A[M,K] @ WT[N2,K]^T ----------------
// BM=64, BN=64, BK=32; 256 thr = 4 waves; wave w owns rows w*16..w*16+15.
// A-frag: lane holds A[m=lane&15][k=quad*8+j]; B-frag: B[n=lane&15][k=quad*8+j];
// C/D: col=lane&15, row=quad*4+reg.
// TA: float (layer-1 x, converted at staging) or ushort_t (bf16 activations).
// EPI: +bias,relu -> fp32 C. else -> bf16 Cb.
template <typename TA, bool EPI>
__global__ __launch_bounds__(256) void gemm_mfma(const TA* __restrict__ A,
                                                 const ushort_t* __restrict__ WT,
                                                 float* __restrict__ C,
                                                 ushort_t* __restrict__ Cb,
                                                 const float* __restrict__ bias,
                                                 int M, int K, int N2) {
    __shared__ ushort_t sA[64 * 32];  // 4 KB
    __shared__ ushort_t sB[64 * 32];  // 4 KB
    const int tid = threadIdx.x;
    const int wv = tid >> 6, lane = tid & 63;
    const int quad = lane >> 4, l16 = lane & 15;
    const int bm = blockIdx.x * 64, bn = blockIdx.y * 64;
    const int srow = tid >> 2, skof = (tid & 3) * 8;
    f32x4 acc[4] = {};

    for (int k0 = 0; k0 < K; k0 += 32) {
        int gm = bm + srow;
        gm = gm < M ? gm : M - 1;  // clamp tail (dup read; epilogue masks)
        stage8(A + (size_t)gm * K + k0 + skof, sA + srow * 32 + skof);
        stage8(WT + (size_t)(bn + srow) * K + k0 + skof, sB + srow * 32 + skof);
        __syncthreads();

        bf16x8 af = *(const bf16x8*)(sA + (wv * 16 + l16) * 32 + quad * 8);
#pragma unroll
        for (int j = 0; j < 4; j++) {
            bf16x8 bf = *(const bf16x8*)(sB + (j * 16 + l16) * 32 + quad * 8);
            acc[j] = __builtin_amdgcn_mfma_f32_16x16x32_bf16(af, bf, acc[j], 0, 0, 0);
        }
        __syncthreads();
    }

#pragma unroll
    for (int j = 0; j < 4; j++) {
        int col = bn + j * 16 + l16;
        float bv = EPI ? bias[col] : 0.f;
#pragma unroll
        for (int r = 0; r < 4; r++) {
            int row = bm + wv * 16 + quad * 4 + r;
            if (row < M) {
                float v = acc[j][r];
                if (EPI) {
                    v += bv;
                    v = v > 0.f ? v : 0.f;
                    C[(size_t)row * N2 + col] = v;
                } else {
                    Cb[(size_t)row * N2 + col] = f2b(v);
                }
            }
        }
    }
}

// ---------------- attention coefficients ----------------
// CH=256: one wave/node; lane l owns channels 4l..4l+3 (head l>>4); ushort4 xl.
// CH=64: one wave/node, scalar.
template <int CH>
__global__ __launch_bounds__(256) void attn_kernel(const ushort_t* __restrict__ xl,
                                                   const float* __restrict__ a_src,
                                                   const float* __restrict__ a_dst,
                                                   float* __restrict__ as_n,
                                                   float* __restrict__ ad_n, int N) {
    int n = blockIdx.x * 4 + (threadIdx.x >> 6);
    int lane = threadIdx.x & 63;
    if (n >= N) return;
    if (CH == 256) {
        ushort4 u = ((const ushort4*)xl)[(size_t)n * 64 + lane];
        float4 av = ((const float4*)a_src)[lane];
        float4 dv = ((const float4*)a_dst)[lane];
        float x0 = b2f(u.x), x1 = b2f(u.y), x2 = b2f(u.z), x3 = b2f(u.w);
        float s = x0 * av.x + x1 * av.y + x2 * av.z + x3 * av.w;
        float d = x0 * dv.x + x1 * dv.y + x2 * dv.z + x3 * dv.w;
#pragma unroll
        for (int off = 8; off; off >>= 1) {
            s += __shfl_xor(s, off, 64);
            d += __shfl_xor(d, off, 64);
        }
        if ((lane & 15) == 0) {
            int h = lane >> 4;
            as_n[n * 4 + h] = s;
            ad_n[n * 4 + h] = d;
        }
    } else {
        float xv = b2f(xl[(size_t)n * 64 + lane]);
        float s = xv * a_src[lane];
        float d = xv * a_dst[lane];
#pragma unroll
        for (int off = 32; off; off >>= 1) {
            s += __shfl_xor(s, off, 64);
            d += __shfl_xor(d, off, 64);
        }
        if (lane == 0) { as_n[n] = s; ad_n[n] = d; }
    }
}

// ---------------- per-dst softmax-weighted aggregation ----------------
// CH=256: lane l owns channels 4l..4l+3 (head l>>4): 1 ushort4 gather + 1 exp/edge.
// CH=64: scalar per lane, single head.
template <int CH>
__global__ __launch_bounds__(256) void aggregate_kernel(const ushort_t* __restrict__ xl,
                                                        const float* __restrict__ as_n,
                                                        const float* __restrict__ ad_n,
                                                        const int* __restrict__ rowoff,
                                                        const int* __restrict__ ssrc,
                                                        const float* __restrict__ bias,
                                                        ushort_t* __restrict__ hout, int N) {
    int dd = blockIdx.x * 4 + (threadIdx.x >> 6);
    int lane = threadIdx.x & 63;
    if (dd >= N) return;
    int r0 = rowoff[dd], r1 = rowoff[dd + 1];
    if (CH == 256) {
        const int h = lane >> 4;
        const float adv = ad_n[dd * 4 + h];
        const ushort4* xv = (const ushort4*)xl;
        float a0 = 0.f, a1 = 0.f, a2 = 0.f, a3 = 0.f, den = 0.f;
        for (int i = r0; i < r1; i++) {
            int s = ssrc[i];
            float lg = as_n[s * 4 + h] + adv;
            lg = lg > 0.f ? lg : 0.2f * lg;
            float p = __expf(lg);
            den += p;
            ushort4 u = xv[(size_t)s * 64 + lane];
            a0 += p * b2f(u.x);
            a1 += p * b2f(u.y);
            a2 += p * b2f(u.z);
            a3 += p * b2f(u.w);
        }
        float di = 1.f / (den + 1e-16f);
        float4 bv = ((const float4*)bias)[lane];
        float v0 = a0 * di + bv.x;
        float v1 = a1 * di + bv.y;
        float v2 = a2 * di + bv.z;
        float v3 = a3 * di + bv.w;
        ushort4 o;
        o.x = f2b(v0 > 0.f ? v0 : 0.f);
        o.y = f2b(v1 > 0.f ? v1 : 0.f);
        o.z = f2b(v2 > 0.f ? v2 : 0.f);
        o.w = f2b(v3 > 0.f ? v3 : 0.f);
        ((ushort4*)hout)[(size_t)dd * 64 + lane] = o;
    } else {
        const float adv = ad_n[dd];
        float a0 = 0.f, den = 0.f;
        for (int i = r0; i < r1; i++) {
            int s = ssrc[i];
            float lg = as_n[s] + adv;
            lg = lg > 0.f ? lg : 0.2f * lg;
            float p = __expf(lg);
            den += p;
            a0 += p * b2f(xl[(size_t)s * 64 + lane]);
        }
        float v = a0 / (den + 1e-16f) + bias[lane];
        hout[(size_t)dd * 64 + lane] = f2b(v > 0.f ? v : 0.f);
    }
}

extern "C" void kernel_launch(void* const* d_in, const int* in_sizes, int n_in,
                              void* d_out, int out_size, void* d_ws, size_t ws_size,
                              hipStream_t stream) {
    const int N = in_sizes[0] / 128;  // 50000
    const int E = in_sizes[1] / 2;    // 800000
    const int Etot = E + N;

    const float* x = (const float*)d_in[0];  // fp32 input
    const int* ei = (const int*)d_in[1];
    const int* ei_src = ei;
    const int* ei_dst = ei + E;
    float* out = (float*)d_out;  // fp32 output

    const float* as1 = (const float*)d_in[3];
    const float* ad1 = (const float*)d_in[4];
    const float* b1  = (const float*)d_in[5];
    const float* as2 = (const float*)d_in[7];
    const float* ad2 = (const float*)d_in[8];
    const float* b2  = (const float*)d_in[9];
    const float* as3 = (const float*)d_in[11];
    const float* ad3 = (const float*)d_in[12];
    const float* b3  = (const float*)d_in[13];
    const float* bfc = (const float*)d_in[15];

    // ---- workspace layout (bf16 activations) ----
    ushort_t* bufX = (ushort_t*)d_ws;            // [N][256] bf16 (xl, GEMM out)
    ushort_t* bufH = bufX + (size_t)N * 256;     // [N][256] bf16 (agg out)
    ushort_t* W1T  = bufH + (size_t)N * 256;     // 256x128 bf16
    ushort_t* W2T  = W1T + 32768;                // 256x256
    ushort_t* W3T  = W2T + 65536;                // 64x256
    ushort_t* WfcT = W3T + 16384;                // 512x64
    float* asn = (float*)(WfcT + 32768);         // N*4
    float* adn = asn + (size_t)N * 4;            // N*4
    int* deg    = (int*)(adn + (size_t)N * 4);   // N
    int* rowoff = deg + N;                       // N+1
    int* cursor = rowoff + N + 1;                // N
    int* ssrc   = cursor + N;                    // Etot

    // weight transposes+converts (fp32 [K][N] -> bf16 [N][K])
    transpose_kernel<<<(128 * 256 + 255) / 256, 256, 0, stream>>>((const float*)d_in[2], W1T, 128, 256);
    transpose_kernel<<<(256 * 256 + 255) / 256, 256, 0, stream>>>((const float*)d_in[6], W2T, 256, 256);
    transpose_kernel<<<(256 * 64 + 255) / 256, 256, 0, stream>>>((const float*)d_in[10], W3T, 256, 64);
    transpose_kernel<<<(64 * 512 + 255) / 256, 256, 0, stream>>>((const float*)d_in[14], WfcT, 64, 512);

    // CSR build
    hipMemsetAsync(deg, 0, (size_t)(3 * N + 1) * sizeof(int), stream);
    int eb = (Etot + 255) / 256;
    degree_kernel<<<eb, 256, 0, stream>>>(ei_dst, deg, E, Etot);
    scan_kernel<<<1, 1024, 0, stream>>>(deg, rowoff, N);
    scatter_kernel<<<eb, 256, 0, stream>>>(ei_src, ei_dst, rowoff, cursor, ssrc, E, Etot);

    const int MB = (N + 63) / 64;  // 782
    int nb4 = (N + 3) / 4;

    // layer 1: x(fp32) @ W1 -> bufX(bf16); attn; aggregate -> bufH(bf16)
    gemm_mfma<float, false><<<dim3(MB, 4), 256, 0, stream>>>(x, W1T, nullptr, bufX, nullptr, N, 128, 256);
    attn_kernel<256><<<nb4, 256, 0, stream>>>(bufX, as1, ad1, asn, adn, N);
    aggregate_kernel<256><<<nb4, 256, 0, stream>>>(bufX, asn, adn, rowoff, ssrc, b1, bufH, N);

    // layer 2
    gemm_mfma<ushort_t, false><<<dim3(MB, 4), 256, 0, stream>>>(bufH, W2T, nullptr, bufX, nullptr, N, 256, 256);
    attn_kernel<256><<<nb4, 256, 0, stream>>>(bufX, as2, ad2, asn, adn, N);
    aggregate_kernel<256><<<nb4, 256, 0, stream>>>(bufX, asn, adn, rowoff, ssrc, b2, bufH, N);

    // layer 3 (H=1, C=64)
    gemm_mfma<ushort_t, false><<<dim3(MB, 1), 256, 0, stream>>>(bufH, W3T, nullptr, bufX, nullptr, N, 256, 64);
    attn_kernel<64><<<nb4, 256, 0, stream>>>(bufX, as3, ad3, asn, adn, N);
    aggregate_kernel<64><<<nb4, 256, 0, stream>>>(bufX, asn, adn, rowoff, ssrc, b3, bufH, N);

    // final fc: relu(bufH[N,64] @ Wfc + bfc) -> fp32 out
    gemm_mfma<ushort_t, true><<<dim3(MB, 8), 256, 0, stream>>>(bufH, WfcT, out, nullptr, bfc, N, 64, 512);
}

// Round 8
// 580.774 us; speedup vs baseline: 1.8695x; 1.1889x over previous
//
#include <hip/hip_runtime.h>
#include <cstdint>
#include <cstddef>

typedef unsigned short ushort_t;
typedef __bf16 bf16x8 __attribute__((ext_vector_type(8)));
typedef float f32x4 __attribute__((ext_vector_type(4)));

__device__ __forceinline__ float b2f(ushort_t u) {
    return __uint_as_float(((unsigned int)u) << 16);
}
__device__ __forceinline__ ushort_t f2b(float f) {
    __bf16 h = (__bf16)f;  // RNE
    return *(ushort_t*)&h;
}

// stage 8 contiguous elements into LDS as bf16 (overloaded on source type)
__device__ __forceinline__ void stage8(const float* __restrict__ g, ushort_t* s) {
    float4 f0 = *(const float4*)g;
    float4 f1 = *(const float4*)(g + 4);
    union { ushort_t u[8]; uint4 v; } t;
    t.u[0] = f2b(f0.x); t.u[1] = f2b(f0.y); t.u[2] = f2b(f0.z); t.u[3] = f2b(f0.w);
    t.u[4] = f2b(f1.x); t.u[5] = f2b(f1.y); t.u[6] = f2b(f1.z); t.u[7] = f2b(f1.w);
    *(uint4*)s = t.v;
}
__device__ __forceinline__ void stage8(const ushort_t* __restrict__ g, ushort_t* s) {
    *(float4*)s = *(const float4*)g;  // already bf16: raw 16B copy
}

// ---------------- weight transpose+convert: WT[n][k] = bf16(W[k][n]) ----------------
__global__ __launch_bounds__(256) void transpose_kernel(const float* __restrict__ W,
                                                        ushort_t* __restrict__ WT,
                                                        int K, int N2) {
    int id = blockIdx.x * 256 + threadIdx.x;
    if (id >= K * N2) return;
    int n = id / K, k = id - n * K;
    WT[id] = f2b(W[k * N2 + n]);
}

// ---------------- CSR build ----------------
__global__ __launch_bounds__(256) void degree_kernel(const int* __restrict__ ei_dst,
                                                     int* __restrict__ deg, int E, int Etot) {
    int e = blockIdx.x * 256 + threadIdx.x;
    if (e >= Etot) return;
    int d = (e < E) ? ei_dst[e] : (e - E);
    atomicAdd(&deg[d], 1);
}

__global__ __launch_bounds__(1024) void scan_kernel(const int* __restrict__ deg,
                                                    int* __restrict__ rowoff, int n) {
    __shared__ int sums[1024];
    int t = threadIdx.x;
    int chunk = (n + 1023) >> 10;
    int start = t * chunk;
    int end = min(start + chunk, n);
    int s = 0;
    for (int i = start; i < end; i++) s += deg[i];
    sums[t] = s;
    __syncthreads();
    for (int off = 1; off < 1024; off <<= 1) {
        int v = (t >= off) ? sums[t - off] : 0;
        __syncthreads();
        sums[t] += v;
        __syncthreads();
    }
    int base = (t == 0) ? 0 : sums[t - 1];
    for (int i = start; i < end; i++) { rowoff[i] = base; base += deg[i]; }
    if (t == 1023) rowoff[n] = sums[1023];
}

__global__ __launch_bounds__(256) void scatter_kernel(const int* __restrict__ ei_src,
                                                      const int* __restrict__ ei_dst,
                                                      const int* __restrict__ rowoff,
                                                      int* __restrict__ cursor,
                                                      int* __restrict__ ssrc, int E, int Etot) {
    int e = blockIdx.x * 256 + threadIdx.x;
    if (e >= Etot) return;
    int s, d;
    if (e < E) { s = ei_src[e]; d = ei_dst[e]; } else { s = d = e - E; }
    int pos = rowoff[d] + atomicAdd(&cursor[d], 1);
    ssrc[pos] = s;
}

// ---------------- MFMA GEMM: C = A[M,K] @ WT[N2,K]^T ----------------
// BM=64, BN=64, BK=32; 256 thr = 4 waves; wave w owns rows w*16..w*16+15.
// A-frag: lane holds A[m=lane&15][k=quad*8+j]; B-frag: B[n=lane&15][k=quad*8+j];
// C/D: col=lane&15, row=quad*4+reg.
template <typename TA, bool EPI>
__global__ __launch_bounds__(256) void gemm_mfma(const TA* __restrict__ A,
                                                 const ushort_t* __restrict__ WT,
                                                 float* __restrict__ C,
                                                 ushort_t* __restrict__ Cb,
                                                 const float* __restrict__ bias,
                                                 int M, int K, int N2) {
    __shared__ ushort_t sA[64 * 32];  // 4 KB
    __shared__ ushort_t sB[64 * 32];  // 4 KB
    const int tid = threadIdx.x;
    const int wv = tid >> 6, lane = tid & 63;
    const int quad = lane >> 4, l16 = lane & 15;
    const int bm = blockIdx.x * 64, bn = blockIdx.y * 64;
    const int srow = tid >> 2, skof = (tid & 3) * 8;
    f32x4 acc[4] = {};

    for (int k0 = 0; k0 < K; k0 += 32) {
        int gm = bm + srow;
        gm = gm < M ? gm : M - 1;  // clamp tail (dup read; epilogue masks)
        stage8(A + (size_t)gm * K + k0 + skof, sA + srow * 32 + skof);
        stage8(WT + (size_t)(bn + srow) * K + k0 + skof, sB + srow * 32 + skof);
        __syncthreads();

        bf16x8 af = *(const bf16x8*)(sA + (wv * 16 + l16) * 32 + quad * 8);
#pragma unroll
        for (int j = 0; j < 4; j++) {
            bf16x8 bf = *(const bf16x8*)(sB + (j * 16 + l16) * 32 + quad * 8);
            acc[j] = __builtin_amdgcn_mfma_f32_16x16x32_bf16(af, bf, acc[j], 0, 0, 0);
        }
        __syncthreads();
    }

#pragma unroll
    for (int j = 0; j < 4; j++) {
        int col = bn + j * 16 + l16;
        float bv = EPI ? bias[col] : 0.f;
#pragma unroll
        for (int r = 0; r < 4; r++) {
            int row = bm + wv * 16 + quad * 4 + r;
            if (row < M) {
                float v = acc[j][r];
                if (EPI) {
                    v += bv;
                    v = v > 0.f ? v : 0.f;
                    C[(size_t)row * N2 + col] = v;
                } else {
                    Cb[(size_t)row * N2 + col] = f2b(v);
                }
            }
        }
    }
}

// ---------------- attention coefficients ----------------
template <int CH>
__global__ __launch_bounds__(256) void attn_kernel(const ushort_t* __restrict__ xl,
                                                   const float* __restrict__ a_src,
                                                   const float* __restrict__ a_dst,
                                                   float* __restrict__ as_n,
                                                   float* __restrict__ ad_n, int N) {
    int n = blockIdx.x * 4 + (threadIdx.x >> 6);
    int lane = threadIdx.x & 63;
    if (n >= N) return;
    if (CH == 256) {
        ushort4 u = ((const ushort4*)xl)[(size_t)n * 64 + lane];
        float4 av = ((const float4*)a_src)[lane];
        float4 dv = ((const float4*)a_dst)[lane];
        float x0 = b2f(u.x), x1 = b2f(u.y), x2 = b2f(u.z), x3 = b2f(u.w);
        float s = x0 * av.x + x1 * av.y + x2 * av.z + x3 * av.w;
        float d = x0 * dv.x + x1 * dv.y + x2 * dv.z + x3 * dv.w;
#pragma unroll
        for (int off = 8; off; off >>= 1) {
            s += __shfl_xor(s, off, 64);
            d += __shfl_xor(d, off, 64);
        }
        if ((lane & 15) == 0) {
            int h = lane >> 4;
            as_n[n * 4 + h] = s;
            ad_n[n * 4 + h] = d;
        }
    } else {
        float xv = b2f(xl[(size_t)n * 64 + lane]);
        float s = xv * a_src[lane];
        float d = xv * a_dst[lane];
#pragma unroll
        for (int off = 32; off; off >>= 1) {
            s += __shfl_xor(s, off, 64);
            d += __shfl_xor(d, off, 64);
        }
        if (lane == 0) { as_n[n] = s; ad_n[n] = d; }
    }
}

// ---------------- per-dst softmax-weighted aggregation (unroll-4 MLP) ----------------
// CH=256: lane l owns channels 4l..4l+3 (head l>>4): 1 ushort4 gather + 1 exp/edge.
// Edge loop unrolled x4 with batched loads => ~4 gathers in flight per wave.
template <int CH>
__global__ __launch_bounds__(256) void aggregate_kernel(const ushort_t* __restrict__ xl,
                                                        const float* __restrict__ as_n,
                                                        const float* __restrict__ ad_n,
                                                        const int* __restrict__ rowoff,
                                                        const int* __restrict__ ssrc,
                                                        const float* __restrict__ bias,
                                                        ushort_t* __restrict__ hout, int N) {
    int dd = blockIdx.x * 4 + (threadIdx.x >> 6);
    int lane = threadIdx.x & 63;
    if (dd >= N) return;
    int r0 = rowoff[dd], r1 = rowoff[dd + 1];
    if (CH == 256) {
        const int h = lane >> 4;
        const float adv = ad_n[dd * 4 + h];
        const ushort4* xv = (const ushort4*)xl;
        float a0 = 0.f, a1 = 0.f, a2 = 0.f, a3 = 0.f, den = 0.f;
        int i = r0;
        for (; i + 4 <= r1; i += 4) {
            // batch all loads first (independent -> 4 gathers in flight)
            int s0 = ssrc[i], s1 = ssrc[i + 1], s2 = ssrc[i + 2], s3 = ssrc[i + 3];
            float g0 = as_n[s0 * 4 + h], g1 = as_n[s1 * 4 + h];
            float g2 = as_n[s2 * 4 + h], g3 = as_n[s3 * 4 + h];
            ushort4 u0 = xv[(size_t)s0 * 64 + lane];
            ushort4 u1 = xv[(size_t)s1 * 64 + lane];
            ushort4 u2 = xv[(size_t)s2 * 64 + lane];
            ushort4 u3 = xv[(size_t)s3 * 64 + lane];
            float l0 = g0 + adv; l0 = l0 > 0.f ? l0 : 0.2f * l0;
            float l1 = g1 + adv; l1 = l1 > 0.f ? l1 : 0.2f * l1;
            float l2 = g2 + adv; l2 = l2 > 0.f ? l2 : 0.2f * l2;
            float l3 = g3 + adv; l3 = l3 > 0.f ? l3 : 0.2f * l3;
            float p0 = __expf(l0), p1 = __expf(l1), p2 = __expf(l2), p3 = __expf(l3);
            den += p0 + p1 + p2 + p3;
            a0 += p0 * b2f(u0.x) + p1 * b2f(u1.x) + p2 * b2f(u2.x) + p3 * b2f(u3.x);
            a1 += p0 * b2f(u0.y) + p1 * b2f(u1.y) + p2 * b2f(u2.y) + p3 * b2f(u3.y);
            a2 += p0 * b2f(u0.z) + p1 * b2f(u1.z) + p2 * b2f(u2.z) + p3 * b2f(u3.z);
            a3 += p0 * b2f(u0.w) + p1 * b2f(u1.w) + p2 * b2f(u2.w) + p3 * b2f(u3.w);
        }
        for (; i < r1; i++) {
            int s = ssrc[i];
            float lg = as_n[s * 4 + h] + adv;
            lg = lg > 0.f ? lg : 0.2f * lg;
            float p = __expf(lg);
            den += p;
            ushort4 u = xv[(size_t)s * 64 + lane];
            a0 += p * b2f(u.x);
            a1 += p * b2f(u.y);
            a2 += p * b2f(u.z);
            a3 += p * b2f(u.w);
        }
        float di = 1.f / (den + 1e-16f);
        float4 bv = ((const float4*)bias)[lane];
        float v0 = a0 * di + bv.x;
        float v1 = a1 * di + bv.y;
        float v2 = a2 * di + bv.z;
        float v3 = a3 * di + bv.w;
        ushort4 o;
        o.x = f2b(v0 > 0.f ? v0 : 0.f);
        o.y = f2b(v1 > 0.f ? v1 : 0.f);
        o.z = f2b(v2 > 0.f ? v2 : 0.f);
        o.w = f2b(v3 > 0.f ? v3 : 0.f);
        ((ushort4*)hout)[(size_t)dd * 64 + lane] = o;
    } else {
        const float adv = ad_n[dd];
        float a0 = 0.f, den = 0.f;
        int i = r0;
        for (; i + 4 <= r1; i += 4) {
            int s0 = ssrc[i], s1 = ssrc[i + 1], s2 = ssrc[i + 2], s3 = ssrc[i + 3];
            float g0 = as_n[s0], g1 = as_n[s1], g2 = as_n[s2], g3 = as_n[s3];
            ushort_t u0 = xl[(size_t)s0 * 64 + lane];
            ushort_t u1 = xl[(size_t)s1 * 64 + lane];
            ushort_t u2 = xl[(size_t)s2 * 64 + lane];
            ushort_t u3 = xl[(size_t)s3 * 64 + lane];
            float l0 = g0 + adv; l0 = l0 > 0.f ? l0 : 0.2f * l0;
            float l1 = g1 + adv; l1 = l1 > 0.f ? l1 : 0.2f * l1;
            float l2 = g2 + adv; l2 = l2 > 0.f ? l2 : 0.2f * l2;
            float l3 = g3 + adv; l3 = l3 > 0.f ? l3 : 0.2f * l3;
            float p0 = __expf(l0), p1 = __expf(l1), p2 = __expf(l2), p3 = __expf(l3);
            den += p0 + p1 + p2 + p3;
            a0 += p0 * b2f(u0) + p1 * b2f(u1) + p2 * b2f(u2) + p3 * b2f(u3);
        }
        for (; i < r1; i++) {
            int s = ssrc[i];
            float lg = as_n[s] + adv;
            lg = lg > 0.f ? lg : 0.2f * lg;
            float p = __expf(lg);
            den += p;
            a0 += p * b2f(xl[(size_t)s * 64 + lane]);
        }
        float v = a0 / (den + 1e-16f) + bias[lane];
        hout[(size_t)dd * 64 + lane] = f2b(v > 0.f ? v : 0.f);
    }
}

extern "C" void kernel_launch(void* const* d_in, const int* in_sizes, int n_in,
                              void* d_out, int out_size, void* d_ws, size_t ws_size,
                              hipStream_t stream) {
    const int N = in_sizes[0] / 128;  // 50000
    const int E = in_sizes[1] / 2;    // 800000
    const int Etot = E + N;

    const float* x = (const float*)d_in[0];  // fp32 input
    const int* ei = (const int*)d_in[1];
    const int* ei_src = ei;
    const int* ei_dst = ei + E;
    float* out = (float*)d_out;  // fp32 output

    const float* as1 = (const float*)d_in[3];
    const float* ad1 = (const float*)d_in[4];
    const float* b1  = (const float*)d_in[5];
    const float* as2 = (const float*)d_in[7];
    const float* ad2 = (const float*)d_in[8];
    const float* b2  = (const float*)d_in[9];
    const float* as3 = (const float*)d_in[11];
    const float* ad3 = (const float*)d_in[12];
    const float* b3  = (const float*)d_in[13];
    const float* bfc = (const float*)d_in[15];

    // ---- workspace layout (bf16 activations) ----
    ushort_t* bufX = (ushort_t*)d_ws;            // [N][256] bf16 (xl, GEMM out)
    ushort_t* bufH = bufX + (size_t)N * 256;     // [N][256] bf16 (agg out)
    ushort_t* W1T  = bufH + (size_t)N * 256;     // 256x128 bf16
    ushort_t* W2T  = W1T + 32768;                // 256x256
    ushort_t* W3T  = W2T + 65536;                // 64x256
    ushort_t* WfcT = W3T + 16384;                // 512x64
    float* asn = (float*)(WfcT + 32768);         // N*4
    float* adn = asn + (size_t)N * 4;            // N*4
    int* deg    = (int*)(adn + (size_t)N * 4);   // N
    int* rowoff = deg + N;                       // N+1
    int* cursor = rowoff + N + 1;                // N
    int* ssrc   = cursor + N;                    // Etot

    // weight transposes+converts (fp32 [K][N] -> bf16 [N][K])
    transpose_kernel<<<(128 * 256 + 255) / 256, 256, 0, stream>>>((const float*)d_in[2], W1T, 128, 256);
    transpose_kernel<<<(256 * 256 + 255) / 256, 256, 0, stream>>>((const float*)d_in[6], W2T, 256, 256);
    transpose_kernel<<<(256 * 64 + 255) / 256, 256, 0, stream>>>((const float*)d_in[10], W3T, 256, 64);
    transpose_kernel<<<(64 * 512 + 255) / 256, 256, 0, stream>>>((const float*)d_in[14], WfcT, 64, 512);

    // CSR build
    hipMemsetAsync(deg, 0, (size_t)(3 * N + 1) * sizeof(int), stream);
    int eb = (Etot + 255) / 256;
    degree_kernel<<<eb, 256, 0, stream>>>(ei_dst, deg, E, Etot);
    scan_kernel<<<1, 1024, 0, stream>>>(deg, rowoff, N);
    scatter_kernel<<<eb, 256, 0, stream>>>(ei_src, ei_dst, rowoff, cursor, ssrc, E, Etot);

    const int MB = (N + 63) / 64;  // 782
    int nb4 = (N + 3) / 4;

    // layer 1: x(fp32) @ W1 -> bufX(bf16); attn; aggregate -> bufH(bf16)
    gemm_mfma<float, false><<<dim3(MB, 4), 256, 0, stream>>>(x, W1T, nullptr, bufX, nullptr, N, 128, 256);
    attn_kernel<256><<<nb4, 256, 0, stream>>>(bufX, as1, ad1, asn, adn, N);
    aggregate_kernel<256><<<nb4, 256, 0, stream>>>(bufX, asn, adn, rowoff, ssrc, b1, bufH, N);

    // layer 2
    gemm_mfma<ushort_t, false><<<dim3(MB, 4), 256, 0, stream>>>(bufH, W2T, nullptr, bufX, nullptr, N, 256, 256);
    attn_kernel<256><<<nb4, 256, 0, stream>>>(bufX, as2, ad2, asn, adn, N);
    aggregate_kernel<256><<<nb4, 256, 0, stream>>>(bufX, asn, adn, rowoff, ssrc, b2, bufH, N);

    // layer 3 (H=1, C=64)
    gemm_mfma<ushort_t, false><<<dim3(MB, 1), 256, 0, stream>>>(bufH, W3T, nullptr, bufX, nullptr, N, 256, 64);
    attn_kernel<64><<<nb4, 256, 0, stream>>>(bufX, as3, ad3, asn, adn, N);
    aggregate_kernel<64><<<nb4, 256, 0, stream>>>(bufX, asn, adn, rowoff, ssrc, b3, bufH, N);

    // final fc: relu(bufH[N,64] @ Wfc + bfc) -> fp32 out
    gemm_mfma<ushort_t, true><<<dim3(MB, 8), 256, 0, stream>>>(bufH, WfcT, out, nullptr, bfc, N, 64, 512);
}